// Round 2
// baseline (297.117 us; speedup 1.0000x reference)
//
#include <hip/hip_runtime.h>
#include <hip/hip_cooperative_groups.h>

// ACT-LSTM forward, MI355X (gfx950).
// I=1024, H=2048, O=1024, 4H=8192, MAX_STEPS=20, thresh=0.99.
//
// Math: straight-through Binarize makes the forward output EXACTLY the values
// at the first halting step t* (b is exactly one-hot in fp32: Sterbenz), and
// ponder == t*. With these inputs p ~= sigmoid(1 +- 0.2) ~= 0.73/step, so
// t* = 1 -> only 2 LSTM steps of work (128 MB of W_hh instead of 1.28 GB).
//
// Round-1 failure analysis: absmax 0.578 == max|ref_output| => d_out stayed
// zero => cooperative launch was silently rejected (1024 blocks needed
// 4 blocks/CU co-residency; VGPRs likely >128). Fix: 512 blocks (needs only
// 2 blocks/CU, valid for any VGPR<=256) + __launch_bounds__(256,2) + check
// the launch error and fall back to a plain multi-kernel sequence.

#define NB    512       // blocks: 2/CU co-residency requirement (always valid)
#define BT    256       // threads/block = 4 waves (wave = gate i,f,g,o)
#define CPB   4         // h-columns owned per block (NB*CPB == H)
#define HDIM  2048
#define IDIM  1024
#define G4    8192      // 4*H
#define MAXS  20

static_assert(NB * CPB == HDIM, "columns must tile H");

__device__ __attribute__((aligned(16))) float g_h[2][HDIM];  // dbuf hidden
__device__ float g_c[HDIM];          // cell state (owner-thread access only)
__device__ float g_part[2][NB];      // dbuf halting partials (one per block)

// fallback-path state
__device__ float g_z[G4];            // z = W_ih[:,1:]@x + b_ih + b_hh
__device__ float g_cum;
__device__ int   g_done, g_tstar, g_curbuf;

__device__ __forceinline__ float wave_reduce(float v) {
  #pragma unroll
  for (int off = 32; off; off >>= 1) v += __shfl_xor(v, off, 64);
  return v;  // full 64-lane sum, present on all lanes
}
__device__ __forceinline__ float sigf(float v) {
  return 1.0f / (1.0f + expf(-v));
}

// ---------------------------------------------------------------- coop path
__global__ __launch_bounds__(BT, 2) void act_lstm(
    const float* __restrict__ x,      const float* __restrict__ h_in,
    const float* __restrict__ c_in,   const float* __restrict__ W_ih,
    const float* __restrict__ W_hh,   const float* __restrict__ b_ih,
    const float* __restrict__ b_hh,   const float* __restrict__ w_halt,
    const float* __restrict__ b_halt, const float* __restrict__ W_out,
    const float* __restrict__ b_out,  float* __restrict__ out)
{
  cooperative_groups::grid_group grid = cooperative_groups::this_grid();
  const int tid  = threadIdx.x;
  const int w    = tid >> 6;         // wave id == gate id
  const int lane = tid & 63;
  const int j0   = blockIdx.x * CPB; // owned h-columns j0..j0+3
  const int r0   = w * HDIM + j0;    // gate-w rows for those columns

  // ---- Phase A (once): z = W_ih[:,1:]@x + b_ih + b_hh for 4 rows ----
  float z[CPB], w0[CPB];
  {
    float s[CPB] = {0.f, 0.f, 0.f, 0.f};
    for (int k = 0; k < IDIM / 64; ++k) {     // coalesced scalar loads
      const int c  = k * 64 + lane;
      const float xv = x[c];
      #pragma unroll
      for (int t = 0; t < CPB; ++t)
        s[t] += W_ih[(size_t)(r0 + t) * (IDIM + 1) + 1 + c] * xv;
    }
    #pragma unroll
    for (int t = 0; t < CPB; ++t) {
      z[t]  = wave_reduce(s[t]) + b_ih[r0 + t] + b_hh[r0 + t];
      w0[t] = W_ih[(size_t)(r0 + t) * (IDIM + 1)];   // flag column (step 0)
    }
  }
  const float bh = b_halt[0];

  __shared__ float gsm[4][CPB];  // staged gate values [gate][local col]
  __shared__ float pvs[CPB];     // halting contribution of owned columns
  __shared__ float ssm4[4];      // per-wave partials of global halting sum
  __shared__ float osm[4];       // epilogue per-wave partials

  const float4* Whh4 = reinterpret_cast<const float4*>(W_hh);

  float cum = 0.f;
  int tstar = MAXS - 1;
  int cur   = 0;

  for (int step = 0; step < MAXS; ++step) {
    cur = step & 1;
    const float4* h4 = reinterpret_cast<const float4*>(
        step == 0 ? h_in : g_h[cur ^ 1]);

    // ---- recurrent dots: 4 rows per wave, shared h loads, float4 ----
    float s[CPB] = {0.f, 0.f, 0.f, 0.f};
    #pragma unroll 2
    for (int k = 0; k < HDIM / 4 / 64; ++k) { // 8 iters
      const int idx = k * 64 + lane;
      const float4 hv = h4[idx];
      #pragma unroll
      for (int t = 0; t < CPB; ++t) {
        const float4 wv = Whh4[(size_t)(r0 + t) * (HDIM / 4) + idx];
        s[t] += wv.x * hv.x + wv.y * hv.y + wv.z * hv.z + wv.w * hv.w;
      }
    }
    #pragma unroll
    for (int t = 0; t < CPB; ++t) {
      const float sr = wave_reduce(s[t]);
      if (lane == 0)
        gsm[w][t] = z[t] + (step == 0 ? w0[t] : 0.f) + sr;
    }
    __syncthreads();

    // ---- pointwise cell update for the 4 owned columns ----
    if (tid < CPB) {
      const int j = j0 + tid;
      const float gi = gsm[0][tid], gf = gsm[1][tid];
      const float gg = gsm[2][tid], go = gsm[3][tid];
      const float co = (step == 0) ? c_in[j] : g_c[j];
      const float cn = sigf(gf) * co + sigf(gi) * tanhf(gg);
      const float hn = sigf(go) * tanhf(cn);
      g_c[j]      = cn;
      g_h[cur][j] = hn;
      pvs[tid]    = w_halt[j] * hn;
    }
    __syncthreads();
    if (tid == 0)
      g_part[cur][blockIdx.x] = (pvs[0] + pvs[1]) + (pvs[2] + pvs[3]);

    grid.sync();

    // ---- identical deterministic halting sum in every block ----
    float ps = g_part[cur][tid] + g_part[cur][tid + 256];
    ps = wave_reduce(ps);
    if (lane == 0) ssm4[w] = ps;
    __syncthreads();
    const float ssum = (ssm4[0] + ssm4[1]) + (ssm4[2] + ssm4[3]);
    cum += sigf(ssum + bh);
    if (cum >= 0.99f) { tstar = step; break; }  // uniform across whole grid
  }

  // ---- epilogue: out = W_out @ h[t*] + b_out; h_out; c_out; ponder ----
  const float* hf = g_h[cur];
  {
    const int rr = blockIdx.x * 2 + (w >> 1);   // waves {0,1}->row0 {2,3}->row1
    const int lt = tid & 127;
    const float4* Wo4 = reinterpret_cast<const float4*>(W_out)
                        + (size_t)rr * (HDIM / 4);
    const float4* hf4 = reinterpret_cast<const float4*>(hf);
    float acc = 0.f;
    #pragma unroll
    for (int k = 0; k < 4; ++k) {               // 4*128 = 512 float4
      const int idx = k * 128 + lt;
      const float4 wv = Wo4[idx];
      const float4 hv = hf4[idx];
      acc += wv.x * hv.x + wv.y * hv.y + wv.z * hv.z + wv.w * hv.w;
    }
    acc = wave_reduce(acc);
    if (lane == 0) osm[w] = acc;
    __syncthreads();
    if (tid == 0) out[blockIdx.x * 2]     = (osm[0] + osm[1]) + b_out[blockIdx.x * 2];
    if (tid == 1) out[blockIdx.x * 2 + 1] = (osm[2] + osm[3]) + b_out[blockIdx.x * 2 + 1];
  }
  if (tid < CPB) {
    const int j = j0 + tid;
    out[1024 + j] = hf[j];     // h_out
    out[3072 + j] = g_c[j];    // c_out
  }
  if (blockIdx.x == 0 && tid == CPB) out[5120] = (float)tstar;  // ponder
}

// ------------------------------------------------------------ fallback path
__global__ void fb_init() {
  g_cum = 0.f; g_done = 0; g_tstar = MAXS - 1; g_curbuf = (MAXS - 1) & 1;
}

__global__ __launch_bounds__(BT) void fb_z(
    const float* __restrict__ x, const float* __restrict__ W_ih,
    const float* __restrict__ b_ih, const float* __restrict__ b_hh)
{
  const int row  = blockIdx.x * 4 + (threadIdx.x >> 6);  // 2048 blocks
  const int lane = threadIdx.x & 63;
  const float* Wr = W_ih + (size_t)row * (IDIM + 1);
  float s = 0.f;
  for (int k = 0; k < IDIM / 64; ++k) {
    const int c = k * 64 + lane;
    s += Wr[1 + c] * x[c];
  }
  s = wave_reduce(s);
  if (lane == 0) g_z[row] = s + b_ih[row] + b_hh[row];
}

__global__ __launch_bounds__(BT) void fb_step(int step,
    const float* __restrict__ h_in, const float* __restrict__ c_in,
    const float* __restrict__ W_ih, const float* __restrict__ W_hh,
    const float* __restrict__ w_halt)
{
  if (g_done) return;
  const int tid = threadIdx.x, w = tid >> 6, lane = tid & 63;
  const int j0 = blockIdx.x * CPB;
  const int r0 = w * HDIM + j0;
  const int cur = step & 1;
  const float4* h4 = reinterpret_cast<const float4*>(
      step == 0 ? h_in : g_h[cur ^ 1]);
  const float4* Whh4 = reinterpret_cast<const float4*>(W_hh);
  float s[CPB] = {0.f, 0.f, 0.f, 0.f};
  #pragma unroll 2
  for (int k = 0; k < HDIM / 4 / 64; ++k) {
    const int idx = k * 64 + lane;
    const float4 hv = h4[idx];
    #pragma unroll
    for (int t = 0; t < CPB; ++t) {
      const float4 wv = Whh4[(size_t)(r0 + t) * (HDIM / 4) + idx];
      s[t] += wv.x * hv.x + wv.y * hv.y + wv.z * hv.z + wv.w * hv.w;
    }
  }
  __shared__ float gsm[4][CPB];
  __shared__ float pvs[CPB];
  #pragma unroll
  for (int t = 0; t < CPB; ++t) {
    const float sr = wave_reduce(s[t]);
    if (lane == 0) {
      float zz = g_z[r0 + t];
      if (step == 0) zz += W_ih[(size_t)(r0 + t) * (IDIM + 1)];
      gsm[w][t] = zz + sr;
    }
  }
  __syncthreads();
  if (tid < CPB) {
    const int j = j0 + tid;
    const float gi = gsm[0][tid], gf = gsm[1][tid];
    const float gg = gsm[2][tid], go = gsm[3][tid];
    const float co = (step == 0) ? c_in[j] : g_c[j];
    const float cn = sigf(gf) * co + sigf(gi) * tanhf(gg);
    const float hn = sigf(go) * tanhf(cn);
    g_c[j]      = cn;
    g_h[cur][j] = hn;
    pvs[tid]    = w_halt[j] * hn;
  }
  __syncthreads();
  if (tid == 0)
    g_part[cur][blockIdx.x] = (pvs[0] + pvs[1]) + (pvs[2] + pvs[3]);
}

__global__ __launch_bounds__(BT) void fb_check(int step,
    const float* __restrict__ b_halt)
{
  if (g_done) return;     // uniform
  const int tid = threadIdx.x, w = tid >> 6, lane = tid & 63;
  const int cur = step & 1;
  float ps = g_part[cur][tid] + g_part[cur][tid + 256];
  ps = wave_reduce(ps);
  __shared__ float sm[4];
  if (lane == 0) sm[w] = ps;
  __syncthreads();
  if (tid == 0) {
    const float ssum = (sm[0] + sm[1]) + (sm[2] + sm[3]);
    const float cum = g_cum + sigf(ssum + b_halt[0]);
    g_cum = cum;
    if (cum >= 0.99f) { g_done = 1; g_tstar = step; g_curbuf = cur; }
  }
}

__global__ __launch_bounds__(BT) void fb_final(
    const float* __restrict__ W_out, const float* __restrict__ b_out,
    float* __restrict__ out)
{
  const int tid = threadIdx.x, w = tid >> 6, lane = tid & 63;
  const int j0 = blockIdx.x * CPB;
  const float* hf = g_h[g_curbuf];
  __shared__ float osm[4];
  const int rr = blockIdx.x * 2 + (w >> 1);
  const int lt = tid & 127;
  const float4* Wo4 = reinterpret_cast<const float4*>(W_out)
                      + (size_t)rr * (HDIM / 4);
  const float4* hf4 = reinterpret_cast<const float4*>(hf);
  float acc = 0.f;
  #pragma unroll
  for (int k = 0; k < 4; ++k) {
    const int idx = k * 128 + lt;
    const float4 wv = Wo4[idx];
    const float4 hv = hf4[idx];
    acc += wv.x * hv.x + wv.y * hv.y + wv.z * hv.z + wv.w * hv.w;
  }
  acc = wave_reduce(acc);
  if (lane == 0) osm[w] = acc;
  __syncthreads();
  if (tid == 0) out[blockIdx.x * 2]     = (osm[0] + osm[1]) + b_out[blockIdx.x * 2];
  if (tid == 1) out[blockIdx.x * 2 + 1] = (osm[2] + osm[3]) + b_out[blockIdx.x * 2 + 1];
  if (tid < CPB) {
    const int j = j0 + tid;
    out[1024 + j] = hf[j];
    out[3072 + j] = g_c[j];
  }
  if (blockIdx.x == 0 && tid == CPB) out[5120] = (float)g_tstar;
}

// ------------------------------------------------------------------- launch
extern "C" void kernel_launch(void* const* d_in, const int* in_sizes, int n_in,
                              void* d_out, int out_size, void* d_ws, size_t ws_size,
                              hipStream_t stream) {
  (void)in_sizes; (void)n_in; (void)d_ws; (void)ws_size; (void)out_size;
  const float* x      = (const float*)d_in[0];
  const float* h      = (const float*)d_in[1];
  const float* c      = (const float*)d_in[2];
  const float* W_ih   = (const float*)d_in[3];
  const float* W_hh   = (const float*)d_in[4];
  const float* b_ih   = (const float*)d_in[5];
  const float* b_hh   = (const float*)d_in[6];
  const float* w_halt = (const float*)d_in[7];
  const float* b_halt = (const float*)d_in[8];
  const float* W_out  = (const float*)d_in[9];
  const float* b_out  = (const float*)d_in[10];
  float* out = (float*)d_out;

  void* args[] = {&x, &h, &c, &W_ih, &W_hh, &b_ih, &b_hh,
                  &w_halt, &b_halt, &W_out, &b_out, &out};
  hipError_t err = hipLaunchCooperativeKernel((void*)act_lstm, dim3(NB),
                                              dim3(BT), args, 0, stream);
  if (err != hipSuccess) {
    // non-cooperative fallback: same math, per-step kernels + device flag
    fb_init<<<1, 1, 0, stream>>>();
    fb_z<<<dim3(G4 / 4), dim3(BT), 0, stream>>>(x, W_ih, b_ih, b_hh);
    for (int s = 0; s < MAXS; ++s) {
      fb_step<<<dim3(NB), dim3(BT), 0, stream>>>(s, h, c, W_ih, W_hh, w_halt);
      fb_check<<<dim3(1), dim3(BT), 0, stream>>>(s, b_halt);
    }
    fb_final<<<dim3(NB), dim3(BT), 0, stream>>>(W_out, b_out, out);
  }
}